// Round 1
// 4720.002 us; speedup vs baseline: 1.7435x; 1.7435x over previous
//
#include <hip/hip_runtime.h>
#include <cstdint>
#include <cstddef>

#define BATCH  8192
#define INDIM  64
#define OUTDIM 64
#define HID    128
#define BT     32          // samples per block
#define NT     512         // 8 waves
#define KP     328         // padded A row length (bf16 elems): 320 + 8
#define COLH0  64          // h0 columns start
#define COLH1  192         // h1 columns start
#define KB0    6           // 192/32 k-blocks layer0
#define KB1    8           // 256/32 k-blocks layer1
#define KBD    4           // 128/32 k-blocks decoder

// packed ws layout. ushort (bf16) region:
#define W0U    0           // 32nt x 6kb x 2term x 512 = 196608 u16
#define W1U    196608      // 32nt x 8kb x 2term x 512 = 262144 u16
#define WDU    458752      // 4nt  x 4kb x 2term x 512 = 16384 u16  (ends 475136 u16 = 950272 B)
// float region (float index into ws):
#define B0F    237568      // 512 f32 (permuted, bih0+bhh0)
#define B1F    238080      // 512 f32
#define BDF    238592      // 64 f32
#define NPACK  238656      // total "elements" for prepack grid (pairs + biases)

typedef unsigned short u16;
typedef __attribute__((ext_vector_type(8))) short bfrag;   // 8 bf16 = 4 VGPR (MFMA A/B)
typedef __attribute__((ext_vector_type(4))) float facc;    // 4 f32  (MFMA C/D 16x16)

__device__ __forceinline__ u16 f2bf(float x) {
  uint32_t u = __float_as_uint(x);
  return (u16)((u + 0x7fffu + ((u >> 16) & 1u)) >> 16);   // RNE
}
__device__ __forceinline__ float bf2f(u16 h) {
  return __uint_as_float(((uint32_t)h) << 16);
}
__device__ __forceinline__ float fsig(float x) { return 1.0f / (1.0f + __expf(-x)); }
__device__ __forceinline__ float ftanh(float x) {
  float e = __expf(2.0f * x);
  return 1.0f - 2.0f / (e + 1.0f);
}
__device__ __forceinline__ facc splat4(float v) {
  facc a; a[0] = v; a[1] = v; a[2] = v; a[3] = v; return a;
}

// 3-term split-bf16 GEMM over one K-range.
// wt = pk + W?U + lane*8 (thread's fragment column). A in LDS [BT][KP] hi/lo.
// Wave w owns N-tiles ntq..ntq+3 (= 4 gate types of unit group w), M-tiles 0,1.
template <int KB>
__device__ __forceinline__ void gemm_block(const u16* __restrict__ wt,
                                           const u16 (&Hhi)[BT][KP],
                                           const u16 (&Hlo)[BT][KP],
                                           int colOff, int c, int g, int ntq,
                                           facc (&acc)[2][4]) {
#pragma unroll
  for (int kb = 0; kb < KB; ++kb) {
    bfrag bh[4], bl[4], ah[2], al[2];
#pragma unroll
    for (int t = 0; t < 4; ++t) {
      const u16* p = wt + (((ntq + t) * KB + kb) * 2) * 512;
      bh[t] = *(const bfrag*)p;            // 1KB coalesced per wave, L2-hit
      bl[t] = *(const bfrag*)(p + 512);
    }
    const int k0 = colOff + kb * 32 + g * 8;
#pragma unroll
    for (int mt = 0; mt < 2; ++mt) {
      ah[mt] = *(const bfrag*)&Hhi[mt * 16 + c][k0];   // ds_read_b128
      al[mt] = *(const bfrag*)&Hlo[mt * 16 + c][k0];
    }
#pragma unroll
    for (int mt = 0; mt < 2; ++mt)
#pragma unroll
      for (int t = 0; t < 4; ++t) {
        facc a = acc[mt][t];
        a = __builtin_amdgcn_mfma_f32_16x16x32_bf16(ah[mt], bh[t], a, 0, 0, 0);
        a = __builtin_amdgcn_mfma_f32_16x16x32_bf16(ah[mt], bl[t], a, 0, 0, 0);
        a = __builtin_amdgcn_mfma_f32_16x16x32_bf16(al[mt], bh[t], a, 0, 0, 0);
        acc[mt][t] = a;
      }
  }
}

__global__ __launch_bounds__(NT, 2) void lstm_kernel(
    const float* __restrict__ x, const void* __restrict__ pkv,
    float* __restrict__ out, int S, int P) {
  // A = [x | h0 | h1] as bf16 hi/lo, row-major [sample][col], padded rows.
  __shared__ __align__(16) u16 Ahi[BT][KP];
  __shared__ __align__(16) u16 Alo[BT][KP];

  const u16* pku = (const u16*)pkv;
  const float* pkf = (const float*)pkv;

  const int tid = threadIdx.x;
  const int lane = tid & 63;
  const int w = tid >> 6;        // wave 0..7 = unit group
  const int c = lane & 15;       // tile col (gate/out col, and A row sel)
  const int g = lane >> 4;       // k-group 0..3
  const int b0 = blockIdx.x * BT;

  for (int i = tid; i < BT * KP; i += NT) {
    (&Ahi[0][0])[i] = 0;
    (&Alo[0][0])[i] = 0;
  }

  float b0r[4], b1r[4];
#pragma unroll
  for (int t = 0; t < 4; ++t) {
    b0r[t] = pkf[B0F + (w * 4 + t) * 16 + c];
    b1r[t] = pkf[B1F + (w * 4 + t) * 16 + c];
  }
  const int ntd = w & 3, mtd = w >> 2;                 // decoder tile of this wave
  const float bdr = pkf[BDF + ntd * 16 + c];

  float c0r[8], c1r[8];   // cell state: [mt*4 + r], unit w*16+c
#pragma unroll
  for (int q = 0; q < 8; ++q) { c0r[q] = 0.f; c1r[q] = 0.f; }

  const u16* w0t = pku + W0U + lane * 8;
  const u16* w1t = pku + W1U + lane * 8;
  const u16* wdt = pku + WDU + lane * 8;

  __syncthreads();

  const int T = S + P;
  for (int step = 0; step < T; ++step) {
    if (step < S) {
      // stage x_t: thread -> sample tid>>4, 4 cols; split hi/lo into LDS
      const int s = tid >> 4, c4 = (tid & 15) * 4;
      const float4 v = *(const float4*)(x + ((size_t)(b0 + s) * S + step) * INDIM + c4);
      float vv[4] = {v.x, v.y, v.z, v.w};
      u16 h4[4], l4[4];
#pragma unroll
      for (int q = 0; q < 4; ++q) {
        h4[q] = f2bf(vv[q]);
        l4[q] = f2bf(vv[q] - bf2f(h4[q]));
      }
      uint2 hp, lp;
      hp.x = (uint32_t)h4[0] | ((uint32_t)h4[1] << 16);
      hp.y = (uint32_t)h4[2] | ((uint32_t)h4[3] << 16);
      lp.x = (uint32_t)l4[0] | ((uint32_t)l4[1] << 16);
      lp.y = (uint32_t)l4[2] | ((uint32_t)l4[3] << 16);
      *(uint2*)&Ahi[s][c4] = hp;
      *(uint2*)&Alo[s][c4] = lp;
    }
    __syncthreads();   // B1: x/feedback + prev h1 visible

    // ---------------- layer 0: A cols [0,192) ----------------
    facc acc[2][4];
#pragma unroll
    for (int mt = 0; mt < 2; ++mt)
#pragma unroll
      for (int t = 0; t < 4; ++t) acc[mt][t] = splat4(b0r[t]);
    gemm_block<KB0>(w0t, Ahi, Alo, 0, c, g, w * 4, acc);
    __syncthreads();   // B2: all GEMM0 reads done before h0 overwrite
#pragma unroll
    for (int mt = 0; mt < 2; ++mt)
#pragma unroll
      for (int r = 0; r < 4; ++r) {
        float gi = fsig(acc[mt][0][r]);
        float gf = fsig(acc[mt][1][r]);
        float gg = ftanh(acc[mt][2][r]);
        float go = fsig(acc[mt][3][r]);
        float cn = fmaf(gf, c0r[mt * 4 + r], gi * gg);
        c0r[mt * 4 + r] = cn;
        float hv = go * ftanh(cn);
        const int s = mt * 16 + g * 4 + r;
        u16 hh = f2bf(hv);
        Ahi[s][COLH0 + w * 16 + c] = hh;
        Alo[s][COLH0 + w * 16 + c] = f2bf(hv - bf2f(hh));
      }
    __syncthreads();   // B3: h0 visible

    // ---------------- layer 1: A cols [64,320) ----------------
#pragma unroll
    for (int mt = 0; mt < 2; ++mt)
#pragma unroll
      for (int t = 0; t < 4; ++t) acc[mt][t] = splat4(b1r[t]);
    gemm_block<KB1>(w1t, Ahi, Alo, COLH0, c, g, w * 4, acc);
    __syncthreads();   // B4: all GEMM1 reads done before h1 overwrite
#pragma unroll
    for (int mt = 0; mt < 2; ++mt)
#pragma unroll
      for (int r = 0; r < 4; ++r) {
        float gi = fsig(acc[mt][0][r]);
        float gf = fsig(acc[mt][1][r]);
        float gg = ftanh(acc[mt][2][r]);
        float go = fsig(acc[mt][3][r]);
        float cn = fmaf(gf, c1r[mt * 4 + r], gi * gg);
        c1r[mt * 4 + r] = cn;
        float hv = go * ftanh(cn);
        const int s = mt * 16 + g * 4 + r;
        u16 hh = f2bf(hv);
        Ahi[s][COLH1 + w * 16 + c] = hh;
        Alo[s][COLH1 + w * 16 + c] = f2bf(hv - bf2f(hh));
      }

    // ---------------- decoder (MFMA) + feedback ----------------
    if (step >= S) {
      __syncthreads();   // B5: h1 visible
      facc da = splat4(bdr);
#pragma unroll
      for (int kb = 0; kb < KBD; ++kb) {
        const u16* p = wdt + ((ntd * KBD + kb) * 2) * 512;
        bfrag wbh = *(const bfrag*)p;
        bfrag wbl = *(const bfrag*)(p + 512);
        const int k0 = COLH1 + kb * 32 + g * 8;
        bfrag dah = *(const bfrag*)&Ahi[mtd * 16 + c][k0];
        bfrag dal = *(const bfrag*)&Alo[mtd * 16 + c][k0];
        da = __builtin_amdgcn_mfma_f32_16x16x32_bf16(dah, wbh, da, 0, 0, 0);
        da = __builtin_amdgcn_mfma_f32_16x16x32_bf16(dah, wbl, da, 0, 0, 0);
        da = __builtin_amdgcn_mfma_f32_16x16x32_bf16(dal, wbh, da, 0, 0, 0);
      }
      const int dstep = step - S;
#pragma unroll
      for (int r = 0; r < 4; ++r) {
        const int s = mtd * 16 + g * 4 + r;
        const int o = ntd * 16 + c;
        float pv = da[r];
        out[((size_t)(b0 + s) * P + dstep) * OUTDIM + o] = pv;
        u16 hh = f2bf(pv);                  // feedback -> next step's x
        Ahi[s][o] = hh;
        Alo[s][o] = f2bf(pv - bf2f(hh));
      }
      // next-iteration B1 makes feedback visible before GEMM0
    }
  }
}

// Pack weights into MFMA-fragment order, bf16 hi/lo; biases permuted + pre-summed.
// Gate permutation: packed n = ug*64 + t*16 + u  <->  torch row = t*128 + ug*16 + u
// Fragment: value at [nt][kb][term][lane][j] = W[k = kb*32 + (lane>>4)*8 + j][gate nt*16 + (lane&15)]
__global__ void prepack_kernel(const float* __restrict__ wih0, const float* __restrict__ whh0,
                               const float* __restrict__ bih0, const float* __restrict__ bhh0,
                               const float* __restrict__ wih1, const float* __restrict__ whh1,
                               const float* __restrict__ bih1, const float* __restrict__ bhh1,
                               const float* __restrict__ wdec, const float* __restrict__ bdec,
                               void* __restrict__ pko) {
  int idx = blockIdx.x * blockDim.x + threadIdx.x;
  if (idx >= NPACK) return;
  u16* pu = (u16*)pko;
  float* pf = (float*)pko;
  if (idx < 98304) {                       // W0: 32nt * 6kb * 512
    int nt = idx / 3072, rem = idx % 3072;
    int kb = rem >> 9, q = rem & 511, ln = q >> 3, j = q & 7;
    int n = nt * 16 + (ln & 15);
    int row = ((n >> 4) & 3) * HID + (n >> 6) * 16 + (n & 15);
    int k = kb * 32 + (ln >> 4) * 8 + j;
    float wv = (k < INDIM) ? wih0[row * INDIM + k] : whh0[row * HID + k - INDIM];
    u16 hi = f2bf(wv), lo = f2bf(wv - bf2f(hi));
    int base = W0U + ((nt * KB0 + kb) * 2) * 512;
    pu[base + q] = hi;
    pu[base + 512 + q] = lo;
  } else if (idx < 229376) {               // W1: 32nt * 8kb * 512
    int r = idx - 98304;
    int nt = r >> 12, rem = r & 4095;
    int kb = rem >> 9, q = rem & 511, ln = q >> 3, j = q & 7;
    int n = nt * 16 + (ln & 15);
    int row = ((n >> 4) & 3) * HID + (n >> 6) * 16 + (n & 15);
    int k = kb * 32 + (ln >> 4) * 8 + j;
    float wv = (k < HID) ? wih1[row * HID + k] : whh1[row * HID + k - HID];
    u16 hi = f2bf(wv), lo = f2bf(wv - bf2f(hi));
    int base = W1U + ((nt * KB1 + kb) * 2) * 512;
    pu[base + q] = hi;
    pu[base + 512 + q] = lo;
  } else if (idx < 237568) {               // W_dec: 4nt * 4kb * 512 (natural out order)
    int r = idx - 229376;
    int nt = r >> 11, rem = r & 2047;
    int kb = rem >> 9, q = rem & 511, ln = q >> 3, j = q & 7;
    int o = nt * 16 + (ln & 15);
    int k = kb * 32 + (ln >> 4) * 8 + j;
    float wv = wdec[o * HID + k];
    u16 hi = f2bf(wv), lo = f2bf(wv - bf2f(hi));
    int base = WDU + ((nt * KBD + kb) * 2) * 512;
    pu[base + q] = hi;
    pu[base + 512 + q] = lo;
  } else if (idx < 238080) {               // b0 permuted + summed
    int n = idx - 237568;
    int row = ((n >> 4) & 3) * HID + (n >> 6) * 16 + (n & 15);
    pf[B0F + n] = bih0[row] + bhh0[row];
  } else if (idx < 238592) {               // b1 permuted + summed
    int n = idx - 238080;
    int row = ((n >> 4) & 3) * HID + (n >> 6) * 16 + (n & 15);
    pf[B1F + n] = bih1[row] + bhh1[row];
  } else {                                 // b_dec
    int o = idx - 238592;
    pf[BDF + o] = bdec[o];
  }
}

extern "C" void kernel_launch(void* const* d_in, const int* in_sizes, int n_in,
                              void* d_out, int out_size, void* d_ws, size_t ws_size,
                              hipStream_t stream) {
  const float* x    = (const float*)d_in[0];
  const float* wih0 = (const float*)d_in[1];
  const float* whh0 = (const float*)d_in[2];
  const float* bih0 = (const float*)d_in[3];
  const float* bhh0 = (const float*)d_in[4];
  const float* wih1 = (const float*)d_in[5];
  const float* whh1 = (const float*)d_in[6];
  const float* bih1 = (const float*)d_in[7];
  const float* bhh1 = (const float*)d_in[8];
  const float* wdec = (const float*)d_in[9];
  const float* bdec = (const float*)d_in[10];
  float* out = (float*)d_out;

  const int S = in_sizes[0] / (BATCH * INDIM);     // 128
  const int P = out_size / (BATCH * OUTDIM);       // 20

  prepack_kernel<<<(NPACK + 255) / 256, 256, 0, stream>>>(
      wih0, whh0, bih0, bhh0, wih1, whh1, bih1, bhh1, wdec, bdec, d_ws);

  lstm_kernel<<<BATCH / BT, NT, 0, stream>>>(x, d_ws, out, S, P);
}